// Round 2
// baseline (256.079 us; speedup 1.0000x reference)
//
#include <hip/hip_runtime.h>

namespace {

constexpr int T = 200;
constexpr int D = 128;
constexpr int CH = 64;
constexpr int NC = 4;  // chunks: 64,64,64,8

typedef float f32x4 __attribute__((ext_vector_type(4)));
typedef short bf16x8 __attribute__((ext_vector_type(8)));

__device__ __forceinline__ short f2bf(float f) {
  unsigned u = __float_as_uint(f);
  return (short)((u + 0x7FFFu + ((u >> 16) & 1u)) >> 16);  // RNE
}

// LDS floats:
// [0,4096)      Kbf: 64 rows x 128 bf16 (256B/row), 16B-slot swizzle: slot ^= (row&15)
// [4096,4608)   spart[8][64]   (reused as pout[4][128] in epilogue)
// [4608,4864)   u2[2][128]
// [4864,4928)   wts[64]
// [4928,4936)   red[8]
constexpr int OFF_SPART = 4096;
constexpr int OFF_U2    = 4608;
constexpr int OFF_WTS   = 4864;
constexpr int OFF_RED   = 4928;
constexpr int SMEM_F    = 4936;

__global__ void pre_kernel(const float* __restrict__ w1, float* __restrict__ fragBmC,
                           float* __restrict__ fragDm, float* __restrict__ sT) {
  int idx = blockIdx.x * 256 + threadIdx.x;  // 64 blocks x 256 = 16384
  {
    int f = idx >> 7, d = idx & 127;  // sT[f][d] = w1[d][f] + w1[d][256+f]
    sT[idx] = w1[(size_t)d * 512 + f] + w1[(size_t)d * 512 + 256 + f];
  }
  // fragment layout: frag[ks][tid][j], tid=(wid,lane): d=wid*16+(lane&15), f=ks*32+((lane>>4)&3)*8+j
  int j = idx & 7, tid = (idx >> 3) & 511, ks = idx >> 12;
  int wid = tid >> 6, lane = tid & 63;
  int lrow = (lane >> 4) & 3, lcol = lane & 15;
  int d = wid * 16 + lcol, f = ks * 32 + lrow * 8 + j;
  fragBmC[idx] = w1[(size_t)d * 512 + 128 + f] - w1[(size_t)d * 512 + 256 + f];
  fragDm[idx]  = w1[(size_t)d * 512 + 384 + f];
}

__global__ __launch_bounds__(512, 8) void din_kernel(
    const float* __restrict__ qg, const float* __restrict__ keysg,
    const void* __restrict__ maskg, const float* __restrict__ w1g,
    const float* __restrict__ b1g, const float* __restrict__ pag,
    const float* __restrict__ w2g, const float* __restrict__ b2g,
    const float* __restrict__ fragBmC, const float* __restrict__ fragDm,
    const float* __restrict__ sT, int usePre, float* __restrict__ outg) {
  __shared__ __align__(16) float smem[SMEM_F];
  float* spart = smem + OFF_SPART;
  float* u2    = smem + OFF_U2;
  float* wts   = smem + OFF_WTS;
  float* red   = smem + OFF_RED;

  const int tid  = threadIdx.x;
  const int b    = blockIdx.x;
  const int wid  = tid >> 6;
  const int lane = tid & 63;
  const int lrow = (lane >> 4) & 3;
  const int lcol = lane & 15;
  const int dw   = wid * 16 + lcol;

  const float* qb    = qg + (size_t)b * D;
  const float* keysB = keysg + (size_t)b * T * D;

  // ---- mask dtype detector (wave-uniform, no barrier) ----
  int mcode;
  {
    unsigned v = ((const unsigned*)maskg)[lane];
    unsigned c0 = v & 255u, c1 = (v >> 8) & 255u, c2 = (v >> 16) & 255u, c3 = v >> 24;
    bool weird = (c0 == 0x80u) | (c0 == 0x3Fu) | (c1 == 0x80u) | (c1 == 0x3Fu) |
                 (c2 == 0x80u) | (c2 == 0x3Fu) | (c3 == 0x80u) | (c3 == 0x3Fu);
    bool nz = (v & 0xFFFFFF00u) != 0u;
    unsigned long long bw = __ballot(weird);
    unsigned long long bn = __ballot(nz);
    mcode = bw ? 2 : (bn ? 1 : 0);  // 2=f32, 1=byte, 0=int32
  }

  const float pa  = pag[0];
  const float b2v = b2g[0];
  const float w2d = w2g[dw];

  // ---- stage chunk 0: keys -> LDS bf16, slot-swizzled ----
  #define STAGE(TBASE2, NFRAG)                                              \
    do {                                                                    \
      _Pragma("unroll")                                                     \
      for (int p = 0; p < 2; ++p) {                                         \
        int fid = p * 512 + tid;                                            \
        if (fid < (NFRAG)) {                                                \
          int row = fid >> 4, fi = fid & 15;                                \
          const float* src = keysB + (size_t)((TBASE2) + row) * D + fi * 8; \
          f32x4 a0 = *(const f32x4*)src;                                    \
          f32x4 a1 = *(const f32x4*)(src + 4);                              \
          bf16x8 v;                                                         \
          v[0] = f2bf(a0.x); v[1] = f2bf(a0.y);                             \
          v[2] = f2bf(a0.z); v[3] = f2bf(a0.w);                             \
          v[4] = f2bf(a1.x); v[5] = f2bf(a1.y);                             \
          v[6] = f2bf(a1.z); v[7] = f2bf(a1.w);                             \
          int slot = fi ^ (row & 15);                                       \
          *(bf16x8*)((char*)smem + row * 256 + slot * 16) = v;              \
        }                                                                   \
      }                                                                     \
    } while (0)

  STAGE(0, CH * 16);

  // ---- M fragments: M[d][f] = (Bm-C)[d][f] + Dm[d][f]*q[f], bf16 B-operand ----
  bf16x8 mfr[4];
  if (usePre) {
    #pragma unroll
    for (int ks = 0; ks < 4; ++ks) {
      int f0 = ks * 32 + lrow * 8;
      const float* base = fragBmC + ((size_t)(ks * 512) + tid) * 8;
      const float* based = fragDm + ((size_t)(ks * 512) + tid) * 8;
      f32x4 m0 = *(const f32x4*)base,  m1 = *(const f32x4*)(base + 4);
      f32x4 d0 = *(const f32x4*)based, d1 = *(const f32x4*)(based + 4);
      f32x4 q0 = *(const f32x4*)(qb + f0), q1 = *(const f32x4*)(qb + f0 + 4);
      bf16x8 m;
      m[0] = f2bf(m0.x + d0.x * q0.x); m[1] = f2bf(m0.y + d0.y * q0.y);
      m[2] = f2bf(m0.z + d0.z * q0.z); m[3] = f2bf(m0.w + d0.w * q0.w);
      m[4] = f2bf(m1.x + d1.x * q1.x); m[5] = f2bf(m1.y + d1.y * q1.y);
      m[6] = f2bf(m1.z + d1.z * q1.z); m[7] = f2bf(m1.w + d1.w * q1.w);
      mfr[ks] = m;
    }
  } else {
    const float* w1row = w1g + (size_t)dw * 512;
    #pragma unroll
    for (int ks = 0; ks < 4; ++ks) {
      int f0 = ks * 32 + lrow * 8;
      f32x4 q0  = *(const f32x4*)(qb + f0),         q1  = *(const f32x4*)(qb + f0 + 4);
      f32x4 bB0 = *(const f32x4*)(w1row + 128 + f0), bB1 = *(const f32x4*)(w1row + 128 + f0 + 4);
      f32x4 cC0 = *(const f32x4*)(w1row + 256 + f0), cC1 = *(const f32x4*)(w1row + 256 + f0 + 4);
      f32x4 dD0 = *(const f32x4*)(w1row + 384 + f0), dD1 = *(const f32x4*)(w1row + 384 + f0 + 4);
      bf16x8 m;
      m[0] = f2bf(bB0.x - cC0.x + dD0.x * q0.x); m[1] = f2bf(bB0.y - cC0.y + dD0.y * q0.y);
      m[2] = f2bf(bB0.z - cC0.z + dD0.z * q0.z); m[3] = f2bf(bB0.w - cC0.w + dD0.w * q0.w);
      m[4] = f2bf(bB1.x - cC1.x + dD1.x * q1.x); m[5] = f2bf(bB1.y - cC1.y + dD1.y * q1.y);
      m[6] = f2bf(bB1.z - cC1.z + dD1.z * q1.z); m[7] = f2bf(bB1.w - cC1.w + dD1.w * q1.w);
      mfr[ks] = m;
    }
  }

  // ---- u[d] = sum_f q[f]*(A+C)[d][f] + b1[d] ----
  if (tid < 256) {
    int d = tid & 127, fh = tid >> 7;
    float acc = 0.f;
    if (usePre) {
      const float* sp = sT + (size_t)(fh * 64) * 128 + d;
      const float* qh = qb + fh * 64;
      #pragma unroll
      for (int i = 0; i < 64; ++i) acc += qh[i] * sp[(size_t)i * 128];
    } else {
      const float* arow = w1g + (size_t)d * 512 + fh * 64;
      const float* crow = arow + 256;
      const float* qh   = qb + fh * 64;
      #pragma unroll
      for (int i = 0; i < 16; ++i) {
        f32x4 qv = *(const f32x4*)(qh + i * 4);
        f32x4 av = *(const f32x4*)(arow + i * 4);
        f32x4 cv = *(const f32x4*)(crow + i * 4);
        acc += qv.x * (av.x + cv.x) + qv.y * (av.y + cv.y) +
               qv.z * (av.z + cv.z) + qv.w * (av.w + cv.w);
      }
    }
    if (fh == 0) acc += b1g[d];
    u2[fh * 128 + d] = acc;
  }

  __syncthreads();  // Kbf(0), u2 ready

  const float u_d = u2[dw] + u2[128 + dw];

  float m_run = -1e9f, denom = 0.f, accPV = 0.f;
  const int dpv = tid & 127, q4 = tid >> 7;

  for (int c = 0; c < NC; ++c) {
    const int tbase = c * CH;
    const int rows_c = (T - tbase < CH) ? (T - tbase) : CH;
    const int nt = (rows_c + 15) >> 4;

    // ---- scores: H = K*M^T (+u via acc-init); PReLU; dot w2; partial over 16 d ----
    for (int tt = 0; tt < nt; ++tt) {
      int row = tt * 16 + lcol;
      f32x4 acc = {u_d, u_d, u_d, u_d};
      const char* rbase = (const char*)smem + row * 256;
      int rx = (row & 15) << 4;
      #pragma unroll
      for (int ks = 0; ks < 4; ++ks) {
        int off = (((ks * 4 + lrow) << 4)) ^ rx;
        bf16x8 af = *(const bf16x8*)(rbase + off);
        acc = __builtin_amdgcn_mfma_f32_16x16x32_bf16(af, mfr[ks], acc, 0, 0, 0);
      }
      #pragma unroll
      for (int j = 0; j < 4; ++j) {
        float h = acc[j];
        h = (h >= 0.f) ? h : pa * h;  // PReLU
        float pj = h * w2d;
        pj += __shfl_xor(pj, 1);
        pj += __shfl_xor(pj, 2);
        pj += __shfl_xor(pj, 4);
        pj += __shfl_xor(pj, 8);
        if (lcol == 0) spart[wid * 64 + tt * 16 + lrow * 4 + j] = pj;
      }
    }
    __syncthreads();  // B1: spart ready; Kbf free for restage

    // ---- wave0: chunk softmax; all waves: stage next chunk ----
    if (wid == 0) {
      float ssum = b2v;
      #pragma unroll
      for (int w = 0; w < 8; ++w) ssum += spart[w * 64 + lane];
      bool valid = (lane < rows_c);
      if (valid) {
        size_t mi = (size_t)b * T + tbase + lane;
        if (mcode == 0)      valid = ((const int*)maskg)[mi] != 0;
        else if (mcode == 1) valid = ((const unsigned char*)maskg)[mi] != 0;
        else                 valid = ((const float*)maskg)[mi] != 0.f;
      }
      float s = valid ? ssum : -1e9f;
      float mm = s;
      #pragma unroll
      for (int o = 1; o < 64; o <<= 1) mm = fmaxf(mm, __shfl_xor(mm, o));
      float mnew = fmaxf(m_run, mm);
      float pv = valid ? __expf(s - mnew) : 0.f;
      wts[lane] = pv;
      float ps = pv;
      #pragma unroll
      for (int o = 1; o < 64; o <<= 1) ps += __shfl_xor(ps, o);
      if (lane == 0) { red[0] = mnew; red[1] = ps; }
    }
    if (c + 1 < NC) {
      int nr = (T - (tbase + CH) < CH) ? (T - (tbase + CH)) : CH;
      STAGE(tbase + CH, nr * 16);
    }
    __syncthreads();  // B2: wts/red ready; Kbf(c+1) ready

    float mnew = red[0], csum = red[1];
    float scale = __expf(m_run - mnew);
    denom = denom * scale + csum;
    m_run = mnew;

    // ---- PV from global keys (L2-hot: just staged) ----
    accPV *= scale;
    const float* krow = keysB + (size_t)tbase * D + dpv;
    #pragma unroll
    for (int i = 0; i < 16; ++i) {
      int trel = q4 * 16 + i;
      float wt = wts[trel];  // wave-uniform
      if (wt != 0.f) accPV += wt * krow[(size_t)trel * D];
    }
  }

  // ---- combine 4 PV partials, normalize, write ----
  spart[q4 * 128 + dpv] = accPV;  // reuse spart as pout[4][128]
  __syncthreads();
  if (tid < 128) {
    float o = spart[tid] + spart[128 + tid] + spart[256 + tid] + spart[384 + tid];
    float inv = (denom > 0.f) ? 1.0f / denom : 0.f;
    outg[(size_t)b * D + tid] = o * inv;
  }
  #undef STAGE
}

}  // namespace

extern "C" void kernel_launch(void* const* d_in, const int* in_sizes, int n_in,
                              void* d_out, int out_size, void* d_ws, size_t ws_size,
                              hipStream_t stream) {
  (void)in_sizes; (void)n_in; (void)out_size;
  const float* q    = (const float*)d_in[0];
  const float* keys = (const float*)d_in[1];
  const void*  mask = d_in[2];
  const float* w1   = (const float*)d_in[3];
  const float* b1   = (const float*)d_in[4];
  const float* pa   = (const float*)d_in[5];
  const float* w2   = (const float*)d_in[6];
  const float* b2   = (const float*)d_in[7];
  float* out = (float*)d_out;

  float* ws = (float*)d_ws;
  int usePre = (ws_size >= (size_t)(3 * 16384) * sizeof(float)) ? 1 : 0;
  float* fB = ws;
  float* fD = ws + 16384;
  float* sT = ws + 32768;
  if (usePre) pre_kernel<<<64, 256, 0, stream>>>(w1, fB, fD, sT);
  din_kernel<<<2048, 512, 0, stream>>>(q, keys, mask, w1, b1, pa, w2, b2,
                                       fB, fD, sT, usePre, out);
}

// Round 3
// 85.800 us; speedup vs baseline: 2.9846x; 2.9846x over previous
//
#include <hip/hip_runtime.h>

namespace {

constexpr int T  = 200;
constexpr int D  = 128;
constexpr int NT = 13;  // ceil(T/16) 16-row tiles

typedef float f32x4 __attribute__((ext_vector_type(4)));
typedef short bf16x8 __attribute__((ext_vector_type(8)));

__device__ __forceinline__ short f2bf(float f) {
  unsigned u = __float_as_uint(f);
  return (short)((u + 0x7FFFu + ((u >> 16) & 1u)) >> 16);  // RNE
}

// LDS floats:
// [0, 8192)      M: 128 rows x 128 bf16 (256B/row), 16B-slot swizzle slot^=(row&15)
// [8192, 8448)   u2[2][128]
// [8448, 9472)   outl[8][128]
// [9472, 9488)   red[16]  (m_w x8, den_w x8)
constexpr int OFF_U2   = 8192;
constexpr int OFF_OUTL = 8448;
constexpr int OFF_RED  = 9472;
constexpr int SMEM_F   = 9488;

__global__ void pre_kernel(const float* __restrict__ w1, float* __restrict__ BmC,
                           float* __restrict__ Dm, float* __restrict__ sT) {
  int idx = blockIdx.x * 256 + threadIdx.x;  // 64 blocks x 256 = 16384
  int d = idx >> 7, f = idx & 127;
  const float* r = w1 + (size_t)d * 512;
  BmC[idx] = r[128 + f] - r[256 + f];
  Dm[idx]  = r[384 + f];
  sT[(size_t)f * 128 + d] = r[f] + r[256 + f];
}

__global__ __launch_bounds__(512, 4) void din_kernel(
    const float* __restrict__ qg, const float* __restrict__ keysg,
    const void* __restrict__ maskg, const float* __restrict__ w1g,
    const float* __restrict__ b1g, const float* __restrict__ pag,
    const float* __restrict__ w2g, const float* __restrict__ b2g,
    const float* __restrict__ BmC, const float* __restrict__ Dm,
    const float* __restrict__ sT, int usePre, float* __restrict__ outg) {
  __shared__ __align__(16) float smem[SMEM_F];
  float* u2   = smem + OFF_U2;
  float* outl = smem + OFF_OUTL;
  float* red  = smem + OFF_RED;

  const int tid  = threadIdx.x;
  const int b    = blockIdx.x;
  const int wid  = tid >> 6;
  const int lane = tid & 63;
  const int lrow = (lane >> 4) & 3;
  const int lcol = lane & 15;

  const float* qb    = qg + (size_t)b * D;
  const float* keysB = keysg + (size_t)b * T * D;

  // ---- mask dtype detector (wave-uniform, no barrier) ----
  int mcode;
  {
    unsigned v = ((const unsigned*)maskg)[lane];
    unsigned c0 = v & 255u, c1 = (v >> 8) & 255u, c2 = (v >> 16) & 255u, c3 = v >> 24;
    bool weird = (c0 == 0x80u) | (c0 == 0x3Fu) | (c1 == 0x80u) | (c1 == 0x3Fu) |
                 (c2 == 0x80u) | (c2 == 0x3Fu) | (c3 == 0x80u) | (c3 == 0x3Fu);
    bool nz = (v & 0xFFFFFF00u) != 0u;
    unsigned long long bw = __ballot(weird);
    unsigned long long bn = __ballot(nz);
    mcode = bw ? 2 : (bn ? 1 : 0);  // 2=f32, 1=byte, 0=int32
  }

  const float pa  = pag[0];
  const float b2v = b2g[0];

  // ---- build M in LDS: M[d][f] = (Bm-C)[d][f] + Dm[d][f]*q[f], bf16, swizzled ----
  #pragma unroll
  for (int i = 0; i < 4; ++i) {
    int e = i * 4096 + tid * 8;
    int d = e >> 7, f = e & 127;
    f32x4 m0, m1, dd0, dd1;
    if (usePre) {
      m0  = *(const f32x4*)(BmC + e);  m1  = *(const f32x4*)(BmC + e + 4);
      dd0 = *(const f32x4*)(Dm + e);   dd1 = *(const f32x4*)(Dm + e + 4);
    } else {
      const float* r = w1g + (size_t)d * 512;
      f32x4 bB0 = *(const f32x4*)(r + 128 + f), bB1 = *(const f32x4*)(r + 128 + f + 4);
      f32x4 cC0 = *(const f32x4*)(r + 256 + f), cC1 = *(const f32x4*)(r + 256 + f + 4);
      m0 = bB0 - cC0; m1 = bB1 - cC1;
      dd0 = *(const f32x4*)(r + 384 + f); dd1 = *(const f32x4*)(r + 384 + f + 4);
    }
    f32x4 q0 = *(const f32x4*)(qb + f), q1 = *(const f32x4*)(qb + f + 4);
    bf16x8 v;
    v[0] = f2bf(m0.x + dd0.x * q0.x); v[1] = f2bf(m0.y + dd0.y * q0.y);
    v[2] = f2bf(m0.z + dd0.z * q0.z); v[3] = f2bf(m0.w + dd0.w * q0.w);
    v[4] = f2bf(m1.x + dd1.x * q1.x); v[5] = f2bf(m1.y + dd1.y * q1.y);
    v[6] = f2bf(m1.z + dd1.z * q1.z); v[7] = f2bf(m1.w + dd1.w * q1.w);
    int slot = (f >> 3) ^ (d & 15);
    *(bf16x8*)((char*)smem + d * 256 + slot * 16) = v;
  }

  // ---- u[d] = sum_f q[f]*(A+C)[d][f] + b1[d], two f-halves ----
  if (tid < 256) {
    int d = tid & 127, fh = tid >> 7;
    float acc = 0.f;
    if (usePre) {
      const float* sp = sT + (size_t)(fh * 64) * 128 + d;
      const float* qh = qb + fh * 64;
      #pragma unroll
      for (int i = 0; i < 64; ++i) acc += qh[i] * sp[(size_t)i * 128];
    } else {
      const float* arow = w1g + (size_t)d * 512 + fh * 64;
      const float* crow = arow + 256;
      const float* qh   = qb + fh * 64;
      #pragma unroll
      for (int i = 0; i < 16; ++i) {
        f32x4 qv = *(const f32x4*)(qh + i * 4);
        f32x4 av = *(const f32x4*)(arow + i * 4);
        f32x4 cv = *(const f32x4*)(crow + i * 4);
        acc += qv.x * (av.x + cv.x) + qv.y * (av.y + cv.y) +
               qv.z * (av.z + cv.z) + qv.w * (av.w + cv.w);
      }
    }
    if (fh == 0) acc += b1g[d];
    u2[fh * 128 + d] = acc;
  }

  __syncthreads();  // barrier 1: M + u2 ready

  float m_w = -1e9f, den_w = 0.f;
  float accpv[32];
  #pragma unroll
  for (int i = 0; i < 32; ++i) accpv[i] = 0.f;

  // ---- per-wave independent t-tiles: wave w owns tiles w and 8+w ----
  for (int rep = 0; rep < 2; ++rep) {
    int tile = wid + rep * 8;
    if (tile >= NT) break;
    int trow = tile * 16 + lcol;
    int trc  = trow < T ? trow : T - 1;

    // K tile -> fp32 regs (A-fragment layout: lane holds row=lcol, f=ks*32+lrow*8+j)
    const float* kr = keysB + (size_t)trc * D + lrow * 8;
    f32x4 k0[4], k1[4];
    #pragma unroll
    for (int ks = 0; ks < 4; ++ks) {
      k0[ks] = *(const f32x4*)(kr + ks * 32);
      k1[ks] = *(const f32x4*)(kr + ks * 32 + 4);
    }
    bf16x8 af[4];
    #pragma unroll
    for (int ks = 0; ks < 4; ++ks) {
      af[ks][0] = f2bf(k0[ks].x); af[ks][1] = f2bf(k0[ks].y);
      af[ks][2] = f2bf(k0[ks].z); af[ks][3] = f2bf(k0[ks].w);
      af[ks][4] = f2bf(k1[ks].x); af[ks][5] = f2bf(k1[ks].y);
      af[ks][6] = f2bf(k1[ks].z); af[ks][7] = f2bf(k1[ks].w);
    }

    // scores: H[t][d] over all 128 d; fold +u, PReLU, *w2 per d-tile
    float sj[4] = {0.f, 0.f, 0.f, 0.f};
    #pragma unroll
    for (int dt = 0; dt < 8; ++dt) {
      int d = dt * 16 + lcol;
      f32x4 acc = {0.f, 0.f, 0.f, 0.f};
      #pragma unroll
      for (int ks = 0; ks < 4; ++ks) {
        bf16x8 bfv = *(const bf16x8*)((const char*)smem + d * 256 +
                                      ((((ks * 4 + lrow)) ^ (d & 15)) << 4));
        acc = __builtin_amdgcn_mfma_f32_16x16x32_bf16(af[ks], bfv, acc, 0, 0, 0);
      }
      float u_d = u2[d] + u2[128 + d];
      float w2d = w2g[d];
      #pragma unroll
      for (int j = 0; j < 4; ++j) {
        float h = acc[j] + u_d;
        h = (h >= 0.f) ? h : pa * h;  // PReLU
        sj[j] += h * w2d;
      }
    }
    // reduce over the 16-lane d-group (bits 0-3)
    #pragma unroll
    for (int o = 1; o < 16; o <<= 1) {
      sj[0] += __shfl_xor(sj[0], o);
      sj[1] += __shfl_xor(sj[1], o);
      sj[2] += __shfl_xor(sj[2], o);
      sj[3] += __shfl_xor(sj[3], o);
    }
    // mask + bias; invalid -> -1e30 so exp underflows to exactly 0
    float mt = -1e30f;
    #pragma unroll
    for (int j = 0; j < 4; ++j) {
      int t = tile * 16 + lrow * 4 + j;
      bool valid = (t < T);
      if (valid) {
        size_t mi = (size_t)b * T + t;
        if (mcode == 0)      valid = ((const int*)maskg)[mi] != 0;
        else if (mcode == 1) valid = ((const unsigned char*)maskg)[mi] != 0;
        else                 valid = ((const float*)maskg)[mi] != 0.f;
      }
      sj[j] = valid ? (sj[j] + b2v) : -1e30f;
      mt = fmaxf(mt, sj[j]);
    }
    mt = fmaxf(mt, __shfl_xor(mt, 16));
    mt = fmaxf(mt, __shfl_xor(mt, 32));

    float mnew  = fmaxf(m_w, mt);
    float scale = __expf(m_w - mnew);
    den_w *= scale;
    #pragma unroll
    for (int i = 0; i < 32; ++i) accpv[i] *= scale;
    m_w = mnew;

    float wj[4], dsum = 0.f;
    #pragma unroll
    for (int j = 0; j < 4; ++j) { wj[j] = __expf(sj[j] - mnew); dsum += wj[j]; }
    dsum += __shfl_xor(dsum, 16);
    dsum += __shfl_xor(dsum, 32);
    den_w += dsum;

    // broadcast wt for this lane's K row (t = tile*16+lcol)
    float tmp = (lcol & 2) ? ((lcol & 1) ? wj[3] : wj[2])
                           : ((lcol & 1) ? wj[1] : wj[0]);
    float wtr = __shfl(tmp, ((lcol >> 2) << 4) | (lcol & 3), 64);

    // PV partial from the fp32 K regs (row=lcol contribution)
    #pragma unroll
    for (int ks = 0; ks < 4; ++ks) {
      accpv[ks * 8 + 0] += wtr * k0[ks].x;
      accpv[ks * 8 + 1] += wtr * k0[ks].y;
      accpv[ks * 8 + 2] += wtr * k0[ks].z;
      accpv[ks * 8 + 3] += wtr * k0[ks].w;
      accpv[ks * 8 + 4] += wtr * k1[ks].x;
      accpv[ks * 8 + 5] += wtr * k1[ks].y;
      accpv[ks * 8 + 6] += wtr * k1[ks].z;
      accpv[ks * 8 + 7] += wtr * k1[ks].w;
    }
  }

  // ---- fold rows across the 16-lane group; write per-wave partials ----
  #pragma unroll
  for (int i = 0; i < 32; ++i) {
    float v = accpv[i];
    v += __shfl_xor(v, 1); v += __shfl_xor(v, 2);
    v += __shfl_xor(v, 4); v += __shfl_xor(v, 8);
    accpv[i] = v;
  }
  if (lcol == 0) {
    #pragma unroll
    for (int ks = 0; ks < 4; ++ks) {
      f32x4 a = {accpv[ks * 8 + 0], accpv[ks * 8 + 1], accpv[ks * 8 + 2], accpv[ks * 8 + 3]};
      f32x4 c = {accpv[ks * 8 + 4], accpv[ks * 8 + 5], accpv[ks * 8 + 6], accpv[ks * 8 + 7]};
      *(f32x4*)(outl + wid * 128 + ks * 32 + lrow * 8)     = a;
      *(f32x4*)(outl + wid * 128 + ks * 32 + lrow * 8 + 4) = c;
    }
  }
  if (lane == 0) { red[wid] = m_w; red[8 + wid] = den_w; }

  __syncthreads();  // barrier 2: partials ready

  if (tid < 128) {
    float M = red[0];
    #pragma unroll
    for (int w = 1; w < 8; ++w) M = fmaxf(M, red[w]);
    float den = 0.f, o = 0.f;
    #pragma unroll
    for (int w = 0; w < 8; ++w) {
      float scw = __expf(red[w] - M);
      den += red[8 + w] * scw;
      o   += outl[w * 128 + tid] * scw;
    }
    float inv = (den > 0.f) ? 1.0f / den : 0.f;
    outg[(size_t)b * D + tid] = o * inv;
  }
}

}  // namespace

extern "C" void kernel_launch(void* const* d_in, const int* in_sizes, int n_in,
                              void* d_out, int out_size, void* d_ws, size_t ws_size,
                              hipStream_t stream) {
  (void)in_sizes; (void)n_in; (void)out_size;
  const float* q    = (const float*)d_in[0];
  const float* keys = (const float*)d_in[1];
  const void*  mask = d_in[2];
  const float* w1   = (const float*)d_in[3];
  const float* b1   = (const float*)d_in[4];
  const float* pa   = (const float*)d_in[5];
  const float* w2   = (const float*)d_in[6];
  const float* b2   = (const float*)d_in[7];
  float* out = (float*)d_out;

  float* ws = (float*)d_ws;
  int usePre = (ws_size >= (size_t)(3 * 16384) * sizeof(float)) ? 1 : 0;
  float* BmC = ws;
  float* Dm  = ws + 16384;
  float* sT  = ws + 32768;
  if (usePre) pre_kernel<<<64, 256, 0, stream>>>(w1, BmC, Dm, sT);
  din_kernel<<<2048, 512, 0, stream>>>(q, keys, mask, w1, b1, pa, w2, b2,
                                       BmC, Dm, sT, usePre, out);
}